// Round 11
// baseline (1126.255 us; speedup 1.0000x reference)
//
#include <hip/hip_runtime.h>
#include <cstdint>
#include <cstddef>

#define M_DIM 8192
#define N_DIM 4096
#define K_DIM 4096

#define BM 256
#define BN 256
#define BK 128   // K bytes per tile = one mfma_scale_16x16x128 K-step

using f32x4 = __attribute__((ext_vector_type(4))) float;
using i32x4 = __attribute__((ext_vector_type(4))) int;
using v8i   = __attribute__((ext_vector_type(8))) int;

// ---------------- fp8 quantize (fp32 -> OCP e4m3fn, RNE via HW cvt) ----------
__device__ __forceinline__ uint32_t pack4_fp8(float a, float b, float c, float d) {
    int v = 0;
    v = __builtin_amdgcn_cvt_pk_fp8_f32(a, b, v, false);  // bytes 0,1
    v = __builtin_amdgcn_cvt_pk_fp8_f32(c, d, v, true);   // bytes 2,3
    return (uint32_t)v;
}

__global__ void quant_fp8(const float* __restrict__ in, uint32_t* __restrict__ out, int n4) {
    int stride = gridDim.x * blockDim.x;
    for (int i = blockIdx.x * blockDim.x + threadIdx.x; i < n4; i += stride) {
        float4 v = reinterpret_cast<const float4*>(in)[i];
        out[i] = pack4_fp8(v.x, v.y, v.z, v.w);
    }
}

// ---------------- MX-fp8 GEMM: C[m][n] = sum_k A[m][k]*B[n][k] ---------------
__device__ __forceinline__ void async16(const void* g, void* l) {
    __builtin_amdgcn_global_load_lds(
        (const __attribute__((address_space(1))) void*)g,
        (__attribute__((address_space(3))) void*)l,
        16, 0, 0);
}

// 256x256 tile, BK=128B, 8 waves (2Mx4N, 128x64 out/wave).
// LDS: 2 buffers x (A[256][128] + B[256][128]) = 128 KiB, XOR-swizzled cols:
//   physical(r,c) holds logical (r, c ^ ((r&7)<<4))  (both-sides swizzle, rule #21)
// Pipeline: prefetch depth 2, counted vmcnt(8) (T4) — never drained to 0 in loop.
__global__ __launch_bounds__(512, 2) void gemm_fp8mx(
    const uint8_t* __restrict__ A,   // [M][K] fp8
    const uint8_t* __restrict__ B,   // [N][K] fp8
    float* __restrict__ C) {         // [M][N] fp32
    __shared__ __align__(16) uint8_t lds[2 * 65536];   // 128 KiB

    const int nbn = N_DIM / BN;                  // 16
    const int nwg = (M_DIM / BM) * nbn;          // 512 (divisible by 8)
    int bid = blockIdx.x;
    int swz = (bid & 7) * (nwg >> 3) + (bid >> 3);   // bijective XCD swizzle (T1)
    int bm = (swz / nbn) * BM;
    int bn = (swz % nbn) * BN;

    int tid  = threadIdx.x;
    int lane = tid & 63;
    int wid  = tid >> 6;
    int wr = wid >> 2;          // 0..1  (M wave row)
    int wc = wid & 3;           // 0..3  (N wave col)

    // ---- staging geometry: 512 thr x 16B = 8KB/issue; A tile 32KB = 4 issues, B same
    int sr = tid >> 3;                 // 0..63 (row within 64-row issue group)
    int sc = (tid & 7) << 4;           // 0..112
    int xc = sc ^ ((sr & 7) << 4);     // pre-swizzled global col (issue rows step by 64)
    const uint8_t* ga = A + (size_t)(bm + sr) * K_DIM + xc;
    const uint8_t* gb = B + (size_t)(bn + sr) * K_DIM + xc;

#define STAGE(ko, p) do {                                                   \
    uint8_t* _dst = lds + (p) * 65536 + tid * 16;                           \
    _Pragma("unroll") for (int _i = 0; _i < 4; ++_i)                        \
        async16(ga + (size_t)(_i * 64) * K_DIM + (ko), _dst + _i * 8192);   \
    _Pragma("unroll") for (int _i = 0; _i < 4; ++_i)                        \
        async16(gb + (size_t)(_i * 64) * K_DIM + (ko), _dst + 32768 + _i * 8192); \
} while (0)

    // ---- fragment read offsets: lane holds row (lane&15), K bytes [(lane>>4)*32,+32)
    int fr = lane & 15;
    int xr = (fr & 7) << 4;            // read-side swizzle (row&7 == fr&7)
    int kc = (lane >> 4) << 5;         // 0,32,64,96
    int ka0 = kc ^ xr;
    int ka1 = (kc + 16) ^ xr;
    int aoff0 = (wr * 128 + fr) * 128 + ka0;            // + m*2048
    int aoff1 = (wr * 128 + fr) * 128 + ka1;
    int boff0 = 32768 + (wc * 64 + fr) * 128 + ka0;     // + n*2048
    int boff1 = 32768 + (wc * 64 + fr) * 128 + ka1;

    f32x4 acc[8][4] = {};

    // ---- prologue: fill both buffers, wait only for buffer 0 (counted vmcnt)
    STAGE(0, 0);
    STAGE(BK, 1);
    asm volatile("s_waitcnt vmcnt(8)" ::: "memory");
    __builtin_amdgcn_s_barrier();
    __builtin_amdgcn_sched_barrier(0);

#pragma unroll 1
    for (int t = 0; t < K_DIM / BK; ++t) {
        const uint8_t* bufp = lds + (t & 1) * 65536;

        // 4 compute phases: quadrant (mh,nh) = 4 A-frags x 2 B-frags x 8 MFMA
#pragma unroll
        for (int p = 0; p < 4; ++p) {
            const int mh = p >> 1, nh = p & 1;
            v8i aF[4], bF[2];
#pragma unroll
            for (int m = 0; m < 4; ++m) {
                union { v8i v; i32x4 q[2]; } u;
                u.q[0] = *(const i32x4*)(bufp + aoff0 + (mh * 4 + m) * 2048);
                u.q[1] = *(const i32x4*)(bufp + aoff1 + (mh * 4 + m) * 2048);
                aF[m] = u.v;
            }
#pragma unroll
            for (int n = 0; n < 2; ++n) {
                union { v8i v; i32x4 q[2]; } u;
                u.q[0] = *(const i32x4*)(bufp + boff0 + (nh * 2 + n) * 2048);
                u.q[1] = *(const i32x4*)(bufp + boff1 + (nh * 2 + n) * 2048);
                bF[n] = u.v;
            }
            __builtin_amdgcn_s_setprio(1);   // T5
#pragma unroll
            for (int m = 0; m < 4; ++m)
#pragma unroll
                for (int n = 0; n < 2; ++n)
                    acc[mh * 4 + m][nh * 2 + n] =
                        __builtin_amdgcn_mfma_scale_f32_16x16x128_f8f6f4(
                            aF[m], bF[n], acc[mh * 4 + m][nh * 2 + n],
                            0, 0,                 // cbsz: A fp8, blgp: B fp8
                            0, 0x7F7F7F7F,        // scale_a = 1.0 (e8m0 127)
                            0, 0x7F7F7F7F);       // scale_b = 1.0
            __builtin_amdgcn_s_setprio(0);
        }

        // my LDS reads must be retired before anyone overwrites this buffer
        asm volatile("s_waitcnt lgkmcnt(0)" ::: "memory");
        __builtin_amdgcn_sched_barrier(0);
        __builtin_amdgcn_s_barrier();          // all waves done reading buf[t&1]

        if (t < K_DIM / BK - 2) {
            STAGE((t + 2) * BK, t & 1);        // overwrite consumed buffer
            asm volatile("s_waitcnt vmcnt(8)" ::: "memory");   // t+1's 8 loads done
        } else {
            asm volatile("s_waitcnt vmcnt(0)" ::: "memory");   // tail drain
        }
        __builtin_amdgcn_s_barrier();          // buf[(t+1)&1] visible to all waves
        __builtin_amdgcn_sched_barrier(0);
    }
#undef STAGE

    // C/D layout (shape-determined, verified r7): col=lane&15, row=(lane>>4)*4+r
    int cr = bm + wr * 128 + ((lane >> 4) << 2);
    int cc = bn + wc * 64 + (lane & 15);
#pragma unroll
    for (int m = 0; m < 8; ++m)
#pragma unroll
        for (int n = 0; n < 4; ++n)
#pragma unroll
            for (int r = 0; r < 4; ++r)
                C[(size_t)(cr + m * 16 + r) * N_DIM + cc + n * 16] = acc[m][n][r];
}

extern "C" void kernel_launch(void* const* d_in, const int* in_sizes, int n_in,
                              void* d_out, int out_size, void* d_ws, size_t ws_size,
                              hipStream_t stream) {
    const float* x = (const float*)d_in[0];   // [M, K] fp32
    const float* w = (const float*)d_in[1];   // [N, K] fp32
    float* out = (float*)d_out;               // [M, N] fp32

    uint8_t* xq = (uint8_t*)d_ws;                       // M*K fp8
    uint8_t* wq = xq + (size_t)M_DIM * K_DIM;           // N*K fp8  (total 50.3 MB)

    quant_fp8<<<2048, 256, 0, stream>>>(x, (uint32_t*)xq, M_DIM * K_DIM / 4);
    quant_fp8<<<1024, 256, 0, stream>>>(w, (uint32_t*)wq, N_DIM * K_DIM / 4);
    gemm_fp8mx<<<(M_DIM / BM) * (N_DIM / BN), 512, 0, stream>>>(xq, wq, out);
}